// Round 22
// baseline (64.534 us; speedup 1.0000x reference)
//
#include <hip/hip_runtime.h>

// ---------- types ----------
typedef __attribute__((ext_vector_type(4)))  float float4_;
typedef __attribute__((ext_vector_type(16))) float f32x16;
typedef __attribute__((ext_vector_type(8)))  int   i32x8;

#define NROWS 8192
#define NKEYS 16384
#define DDIM  256

// exp(x/T) == exp2(x * C_SC)
static constexpr float T_INV = (float)(1.0 / 0.07);
static constexpr float C_SC  = (float)(1.0 / (0.07 * 0.6931471805599453));

// ---------------------------------------------------------------------------
// 32-key-group fragment-linear key layout for the 32x32x64 B operand:
// group G = 32 keys; fragment (G, kk) is a 2048B block at G*8192 + kk*2048.
// Within a block, reading lane l (l&31 = key-in-group, l>>5 = K-half) owns
// 32B at l*32 covering dims [kk*64 + (l>>5)*32, +32) of key G*32 + (l&31).
// prep writes it, gemm reads it (rule #21: one convention, both sides).
// ---------------------------------------------------------------------------

// ---------------------------------------------------------------------------
// Kernel 1: normalize rows; emit fp8 e4m3 (OCP, HW cvt):
//   qs8  [8192][256] fp8: normalized q scaled by C_SC (MFMA A), natural.
//   keys8: 32-key-group fragment layout (above). 0..8191 = q, 8192.. = g.
//   Pterm[row] = dot_f32(q,g)/T ; diagsub[row] = exp2 of fp8-level qq diag
//   (f32 replica; MFMA accum-order delta ~1e-6 rel -> harmless, clamped).
// Also zeroes S and out[0].
// ---------------------------------------------------------------------------
__global__ __launch_bounds__(256) void prep_kernel(
    const float* __restrict__ h, const float* __restrict__ g,
    unsigned int* __restrict__ qs8, unsigned int* __restrict__ keys8,
    float* __restrict__ Pterm, float* __restrict__ diagsub,
    float* __restrict__ S, float* __restrict__ out)
{
  const int row  = blockIdx.x * 4 + (threadIdx.x >> 6);
  const int lane = threadIdx.x & 63;       // 4 dims each
  float4_ hv = *((const float4_*)h + row * 64 + lane);
  float4_ gv = *((const float4_*)g + row * 64 + lane);

  float ssh = hv.x*hv.x + hv.y*hv.y + hv.z*hv.z + hv.w*hv.w;
  float ssg = gv.x*gv.x + gv.y*gv.y + gv.z*gv.z + gv.w*gv.w;
#pragma unroll
  for (int m = 1; m < 64; m <<= 1) {
    ssh += __shfl_xor(ssh, m);
    ssg += __shfl_xor(ssg, m);
  }
  const float sh = 1.0f / fmaxf(sqrtf(ssh), 1e-8f);
  const float sg = 1.0f / fmaxf(sqrtf(ssg), 1e-8f);

  float qn[4] = { hv.x*sh, hv.y*sh, hv.z*sh, hv.w*sh };
  float gn[4] = { gv.x*sg, gv.y*sg, gv.z*sg, gv.w*sg };

  float pd = qn[0]*gn[0] + qn[1]*gn[1] + qn[2]*gn[2] + qn[3]*gn[3];

  // fp8 packs (RNE, saturating). word_sel / byte_sel must be literals.
  int pq = __builtin_amdgcn_cvt_pk_fp8_f32(qn[0], qn[1], 0, 0);
  pq     = __builtin_amdgcn_cvt_pk_fp8_f32(qn[2], qn[3], pq, 1);
  int ps = __builtin_amdgcn_cvt_pk_fp8_f32(qn[0]*C_SC, qn[1]*C_SC, 0, 0);
  ps     = __builtin_amdgcn_cvt_pk_fp8_f32(qn[2]*C_SC, qn[3]*C_SC, ps, 1);
  int pg = __builtin_amdgcn_cvt_pk_fp8_f32(gn[0], gn[1], 0, 0);
  pg     = __builtin_amdgcn_cvt_pk_fp8_f32(gn[2], gn[3], pg, 1);

  float dd =
      __builtin_amdgcn_cvt_f32_fp8(ps, 0) * __builtin_amdgcn_cvt_f32_fp8(pq, 0)
    + __builtin_amdgcn_cvt_f32_fp8(ps, 1) * __builtin_amdgcn_cvt_f32_fp8(pq, 1)
    + __builtin_amdgcn_cvt_f32_fp8(ps, 2) * __builtin_amdgcn_cvt_f32_fp8(pq, 2)
    + __builtin_amdgcn_cvt_f32_fp8(ps, 3) * __builtin_amdgcn_cvt_f32_fp8(pq, 3);

#pragma unroll
  for (int m = 1; m < 64; m <<= 1) {
    pd += __shfl_xor(pd, m);
    dd += __shfl_xor(dd, m);
  }

  qs8[(size_t)row * 64 + lane] = (unsigned int)ps;   // natural, coalesced

  // 32-key-group fragment writes: this lane's dword = dims [lane*4, +4).
  // kk = lane>>4 ; K-half = (lane>>3)&1 ; byte-in-32B = (lane&7)*4.
  char* kb = (char*)keys8;
  const int foff = ((lane >> 4) << 11)
                 + ((((lane >> 3) & 1) << 5) << 5)   // half*32 lanes *32B
                 + ((lane & 7) << 2);
  {
    const int k = row;                     // q keys (global key idx == row)
    *(unsigned int*)(kb + (((size_t)(k >> 5)) << 13) + foff
                     + ((k & 31) << 5)) = (unsigned int)pq;
  }
  {
    const int k = NROWS + row;             // g keys
    *(unsigned int*)(kb + (((size_t)(k >> 5)) << 13) + foff
                     + ((k & 31) << 5)) = (unsigned int)pg;
  }

  if (lane == 0) {
    Pterm[row]   = pd * T_INV;
    diagsub[row] = __builtin_amdgcn_exp2f(dd);
    S[row]       = 0.0f;
    if (row == 0) out[0] = 0.0f;
  }
}

// ---------------------------------------------------------------------------
// Kernel 2: fused MX-fp8 GEMM via 32x32x64 MFMA + exp2 + row-sum.
// r19 skeleton (no LDS staging, no main-loop barriers, verified-passing),
// ONE lever: mfma_scale_f32_32x32x64_f8f6f4 = 131072 FLOP/instr -> HALF the
// MFMA instruction count at the same 4686 TF ubench ceiling. r7-r19 data:
// effective ~100cy per 16x16x128 MFMA vs 8.6cy issue floor, insensitive to
// TLP/prefetch/interleave -> per-INSTRUCTION overhead is the last untested
// explanation; this tests it directly.
// Grid 512 = 128 mtiles (BM=64) x 4 slices. 8 waves: each covers all 64
// rows x 512 private keys (16 groups of 32). D layout (m74/m101, shape-
// determined m121-m128): col = lane&31, row = (reg&3)+8*(reg>>2)+4*(lane>>5).
// ---------------------------------------------------------------------------
#define MFMA3264(A, B, C) __builtin_amdgcn_mfma_scale_f32_32x32x64_f8f6f4( \
    (A), (B), (C), 0, 0, 0, 127, 0, 127)

__global__ __launch_bounds__(512, 1) void nce_gemm(
    const unsigned int* __restrict__ qs8,
    const unsigned int* __restrict__ keys8,
    float* __restrict__ S)
{
  const int tid  = threadIdx.x;
  const int wid  = tid >> 6;
  const int lane = tid & 63;
  const int l31  = lane & 31, lh = lane >> 5;

  const int bid   = blockIdx.x;
  const int slice = bid & 3;               // constant per XCD
  const int mtile = bid >> 2;              // 0..127
  const int m0    = mtile * 64;

  // ---- A fragments: mf(2) x kk(4); lane: row m0+mf*32+l31,
  //      dims [kk*64 + lh*32, +32) from NATURAL qs8 ----
  const char* qb = (const char*)qs8;
  i32x8 a8[2][4];
#pragma unroll
  for (int mf = 0; mf < 2; ++mf) {
    const char* rp = qb + (size_t)(m0 + mf * 32 + l31) * 256 + lh * 32;
#pragma unroll
    for (int kk = 0; kk < 4; ++kk)
      a8[mf][kk] = *(const i32x8*)(rp + kk * 64);
  }

  f32x16 zero16;
#pragma unroll
  for (int r = 0; r < 16; ++r) zero16[r] = 0.0f;

  f32x16 acc[2];
  float Sp[2][16] = {};

  // wave's private keys: 512 = 16 groups of 32; group stride 8192B
  const char* kp = (const char*)keys8 + (((size_t)slice) << 20)
                 + (((size_t)wid) << 17) + (size_t)lane * 32;

#pragma unroll
  for (int g = 0; g < 16; ++g) {
    i32x8 b0 = *(const i32x8*)(kp + (size_t)g * 8192);
    i32x8 b1 = *(const i32x8*)(kp + (size_t)g * 8192 + 2048);
    i32x8 b2 = *(const i32x8*)(kp + (size_t)g * 8192 + 4096);
    i32x8 b3 = *(const i32x8*)(kp + (size_t)g * 8192 + 6144);

    if (g > 0) {                           // harvest prev group (old acc)
#pragma unroll
      for (int mf = 0; mf < 2; ++mf)
#pragma unroll
        for (int r = 0; r < 16; ++r)
          Sp[mf][r] += __builtin_amdgcn_exp2f(acc[mf][r]);
    }

#pragma unroll
    for (int mf = 0; mf < 2; ++mf) {
      f32x16 t = MFMA3264(a8[mf][0], b0, zero16);
      t        = MFMA3264(a8[mf][1], b1, t);
      t        = MFMA3264(a8[mf][2], b2, t);
      acc[mf]  = MFMA3264(a8[mf][3], b3, t);
    }
  }
#pragma unroll
  for (int mf = 0; mf < 2; ++mf)           // last group's harvest
#pragma unroll
    for (int r = 0; r < 16; ++r)
      Sp[mf][r] += __builtin_amdgcn_exp2f(acc[mf][r]);

  // reduce across the 32 key-columns (lanes sharing lh), then atomics
#pragma unroll
  for (int mf = 0; mf < 2; ++mf)
#pragma unroll
    for (int r = 0; r < 16; ++r) {
      float v = Sp[mf][r];
      v += __shfl_xor(v, 1);  v += __shfl_xor(v, 2);
      v += __shfl_xor(v, 4);  v += __shfl_xor(v, 8);
      v += __shfl_xor(v, 16);
      Sp[mf][r] = v;
    }
  if (l31 == 0) {
#pragma unroll
    for (int mf = 0; mf < 2; ++mf)
#pragma unroll
      for (int r = 0; r < 16; ++r)
        atomicAdd(&S[m0 + mf * 32 + (r & 3) + 8 * (r >> 2) + 4 * lh],
                  Sp[mf][r]);
  }
}

// ---------------------------------------------------------------------------
// Kernel 3: loss partials -> atomicAdd(out). 32 blocks x 256 thr = 1 row/thr.
// ---------------------------------------------------------------------------
__global__ __launch_bounds__(256) void finalize_kernel(
    const float* __restrict__ S, const float* __restrict__ Pterm,
    const float* __restrict__ diagsub, float* __restrict__ out)
{
  const int i = blockIdx.x * 256 + threadIdx.x;
  float v = S[i] - diagsub[i];
  float acc = logf(fmaxf(v, 1e-20f)) - Pterm[i];
#pragma unroll
  for (int m = 1; m < 64; m <<= 1) acc += __shfl_xor(acc, m);
  __shared__ float w[4];
  if ((threadIdx.x & 63) == 0) w[threadIdx.x >> 6] = acc;
  __syncthreads();
  if (threadIdx.x == 0)
    atomicAdd(out, (w[0] + w[1] + w[2] + w[3]) * (1.0f / (float)NROWS));
}

// ---------------------------------------------------------------------------
extern "C" void kernel_launch(void* const* d_in, const int* in_sizes, int n_in,
                              void* d_out, int out_size, void* d_ws, size_t ws_size,
                              hipStream_t stream) {
  const float* h  = (const float*)d_in[0];
  const float* hg = (const float*)d_in[1];

  char* ws = (char*)d_ws;
  const size_t OFF_QS   = 0;                      // 2 MB (8192*256 fp8)
  const size_t OFF_KEYS = (size_t)2 << 20;        // 4 MB (16384*256 fp8)
  const size_t OFF_P    = (size_t)6 << 20;        // 32 KB
  const size_t OFF_DIAG = OFF_P + 32 * 1024;      // 32 KB
  const size_t OFF_S    = OFF_DIAG + 32 * 1024;   // 32 KB
  const size_t NEED     = OFF_S + 32 * 1024;
  if (ws_size < NEED) return;

  unsigned int* qs8   = (unsigned int*)(ws + OFF_QS);
  unsigned int* keys8 = (unsigned int*)(ws + OFF_KEYS);
  float* Pterm   = (float*)(ws + OFF_P);
  float* diagsub = (float*)(ws + OFF_DIAG);
  float* S       = (float*)(ws + OFF_S);

  prep_kernel<<<2048, 256, 0, stream>>>(h, hg, qs8, keys8, Pterm, diagsub, S,
                                        (float*)d_out);
  nce_gemm<<<512, 512, 0, stream>>>(qs8, keys8, S);
  finalize_kernel<<<32, 256, 0, stream>>>(S, Pterm, diagsub, (float*)d_out);
}

// Round 23
// 55.865 us; speedup vs baseline: 1.1552x; 1.1552x over previous
//
#include <hip/hip_runtime.h>

// ---------- types ----------
typedef __attribute__((ext_vector_type(4))) float float4_;
typedef __attribute__((ext_vector_type(4))) float f32x4;
typedef __attribute__((ext_vector_type(8))) int   i32x8;

#define NROWS 8192
#define NKEYS 16384
#define DDIM  256

// exp(x/T) == exp2(x * C_SC)
static constexpr float T_INV = (float)(1.0 / 0.07);
static constexpr float C_SC  = (float)(1.0 / (0.07 * 0.6931471805599453));

// ---------------------------------------------------------------------------
// Fragment-linear key layout (verified r8-r19): key-group G = 16 keys.
// Byte address of the 32B B-fragment of (G, kk, lane):
//     G*4096 + kk*2048 + lane*32
// lane = l4*16 + l15 holds key (G*16 + l15), dims [kk*128 + l4*32, +32).
// prep writes it, gemm reads it (rule #21: one convention, both sides).
// ---------------------------------------------------------------------------

// ---------------------------------------------------------------------------
// Kernel 1: normalize rows; emit fp8 e4m3 (OCP, HW cvt):
//   qs8  [8192][256] fp8: normalized q scaled by C_SC (MFMA A), natural.
//   keys8: fragment-linear (above). Keys 0..8191 = q, 8192..16383 = g.
//   Pterm[row] = dot_f32(q,g)/T ; diagsub[row] = exp2 of fp8-level qq diag.
// Also zeroes S and out[0].  (Byte-identical to verified r19 prep.)
// ---------------------------------------------------------------------------
__global__ __launch_bounds__(256) void prep_kernel(
    const float* __restrict__ h, const float* __restrict__ g,
    unsigned int* __restrict__ qs8, unsigned int* __restrict__ keys8,
    float* __restrict__ Pterm, float* __restrict__ diagsub,
    float* __restrict__ S, float* __restrict__ out)
{
  const int row  = blockIdx.x * 4 + (threadIdx.x >> 6);
  const int lane = threadIdx.x & 63;       // 4 dims each
  float4_ hv = *((const float4_*)h + row * 64 + lane);
  float4_ gv = *((const float4_*)g + row * 64 + lane);

  float ssh = hv.x*hv.x + hv.y*hv.y + hv.z*hv.z + hv.w*hv.w;
  float ssg = gv.x*gv.x + gv.y*gv.y + gv.z*gv.z + gv.w*gv.w;
#pragma unroll
  for (int m = 1; m < 64; m <<= 1) {
    ssh += __shfl_xor(ssh, m);
    ssg += __shfl_xor(ssg, m);
  }
  const float sh = 1.0f / fmaxf(sqrtf(ssh), 1e-8f);
  const float sg = 1.0f / fmaxf(sqrtf(ssg), 1e-8f);

  float qn[4] = { hv.x*sh, hv.y*sh, hv.z*sh, hv.w*sh };
  float gn[4] = { gv.x*sg, gv.y*sg, gv.z*sg, gv.w*sg };

  float pd = qn[0]*gn[0] + qn[1]*gn[1] + qn[2]*gn[2] + qn[3]*gn[3];

  // fp8 packs (RNE, saturating). word_sel / byte_sel must be literals.
  int pq = __builtin_amdgcn_cvt_pk_fp8_f32(qn[0], qn[1], 0, 0);
  pq     = __builtin_amdgcn_cvt_pk_fp8_f32(qn[2], qn[3], pq, 1);
  int ps = __builtin_amdgcn_cvt_pk_fp8_f32(qn[0]*C_SC, qn[1]*C_SC, 0, 0);
  ps     = __builtin_amdgcn_cvt_pk_fp8_f32(qn[2]*C_SC, qn[3]*C_SC, ps, 1);
  int pg = __builtin_amdgcn_cvt_pk_fp8_f32(gn[0], gn[1], 0, 0);
  pg     = __builtin_amdgcn_cvt_pk_fp8_f32(gn[2], gn[3], pg, 1);

  float dd =
      __builtin_amdgcn_cvt_f32_fp8(ps, 0) * __builtin_amdgcn_cvt_f32_fp8(pq, 0)
    + __builtin_amdgcn_cvt_f32_fp8(ps, 1) * __builtin_amdgcn_cvt_f32_fp8(pq, 1)
    + __builtin_amdgcn_cvt_f32_fp8(ps, 2) * __builtin_amdgcn_cvt_f32_fp8(pq, 2)
    + __builtin_amdgcn_cvt_f32_fp8(ps, 3) * __builtin_amdgcn_cvt_f32_fp8(pq, 3);

#pragma unroll
  for (int m = 1; m < 64; m <<= 1) {
    pd += __shfl_xor(pd, m);
    dd += __shfl_xor(dd, m);
  }

  qs8[(size_t)row * 64 + lane] = (unsigned int)ps;   // natural, coalesced

  // fragment-linear key writes: this lane's dword = dims [lane*4, lane*4+4)
  // kk = lane>>5 ; l4 = (lane>>3)&3 ; inner byte = (lane&7)*4
  char* kb = (char*)keys8;
  const int foff = ((lane >> 5) << 11) + (((lane >> 3) & 3) << 9)
                 + ((lane & 7) << 2);
  {
    const int k = row;                     // q keys
    *(unsigned int*)(kb + (((size_t)(k >> 4)) << 12) + foff
                     + ((k & 15) << 5)) = (unsigned int)pq;
  }
  {
    const int k = NROWS + row;             // g keys
    *(unsigned int*)(kb + (((size_t)(k >> 4)) << 12) + foff
                     + ((k & 15) << 5)) = (unsigned int)pg;
  }

  if (lane == 0) {
    Pterm[row]   = pd * T_INV;
    diagsub[row] = __builtin_amdgcn_exp2f(dd);
    S[row]       = 0.0f;
    if (row == 0) out[0] = 0.0f;           // finalize accumulates atomically
  }
}

// ---------------------------------------------------------------------------
// Kernel 2: fused MX-fp8 GEMM (16x16x128) + exp2 + row-sum — r19's verified
// skeleton (no LDS staging, no main-loop barriers, depth-2 B-prefetch,
// BM=64, grid 512). ONE delta vs r19: PARITY-SPLIT ACCUMULATORS with
// 2-group-deferred harvest. r19 issued exp2(acc[g-1]) ~8cy after acc's
// final MFMA — if mfma_scale result latency is O(100+)cy, every group
// stalls there (prefetch can't fix: stall is on acc, not loads; TLP can't
// fix: both waves stall identically). Now exp2(accX) reads a value
// produced TWO groups (~480cy) earlier. g&1 / g%3 fold to constants under
// full unroll (rule #20-safe — r19 compiled this pattern at VGPR 84).
// ---------------------------------------------------------------------------
__global__ __launch_bounds__(512, 1) void nce_gemm(
    const unsigned int* __restrict__ qs8,
    const unsigned int* __restrict__ keys8,
    float* __restrict__ S)
{
  __shared__ float sred[64];               // end-of-kernel reduce only

  const int tid  = threadIdx.x;
  const int wid  = tid >> 6;
  const int lane = tid & 63;
  const int l15  = lane & 15, l4 = lane >> 4;

  const int bid   = blockIdx.x;
  const int slice = bid & 3;               // constant per XCD
  const int mtile = bid >> 2;              // 0..127
  const int m0    = mtile * 64;            // all 8 waves share these 64 rows

  if (tid < 64) sred[tid] = 0.0f;

  // ---- A fragments: 4 mf x 2 kk x 32B ; K elem = kk*128 + l4*32 + j ----
  const char* qb = (const char*)qs8;
  i32x8 a8[4][2];
#pragma unroll
  for (int mf = 0; mf < 4; ++mf) {
    const char* rp = qb + (size_t)(m0 + mf * 16 + l15) * 256 + l4 * 32;
#pragma unroll
    for (int kk = 0; kk < 2; ++kk)
      a8[mf][kk] = *(const i32x8*)(rp + kk * 128);
  }

  const f32x4 zero4 = { 0.f, 0.f, 0.f, 0.f };
  f32x4 accA[4], accB[4];                  // parity-split accumulator sets
  float Sp[4][4] = {};                     // [mf][q] row-sums

  // wave's private key range: 512 keys = 32 groups of 16
  const char* kp = (const char*)keys8
      + (((size_t)(slice * 256 + wid * 32)) << 12) + (size_t)lane * 32;

  // ---- depth-2 B-prefetch: 3-slot rotating buffer (verified r19) ----
  i32x8 b0[3], b1[3];
  b0[0] = *(const i32x8*)(kp);
  b1[0] = *(const i32x8*)(kp + 2048);
  b0[1] = *(const i32x8*)(kp + 4096);
  b1[1] = *(const i32x8*)(kp + 4096 + 2048);

#pragma unroll
  for (int g = 0; g < 32; ++g) {
    if (g + 2 < 32) {                      // prefetch g+2 (compile-time slot)
      b0[(g + 2) % 3] = *(const i32x8*)(kp + ((size_t)(g + 2) << 12));
      b1[(g + 2) % 3] = *(const i32x8*)(kp + ((size_t)(g + 2) << 12) + 2048);
    }

    // harvest the SAME-PARITY acc produced at iteration g-2 (~480cy old),
    // BEFORE this iteration's MFMAs overwrite it (WAR -> renaming-safe).
    if ((g & 1) == 0) {
      if (g >= 2) {
#pragma unroll
        for (int mf = 0; mf < 4; ++mf)
#pragma unroll
          for (int q = 0; q < 4; ++q)
            Sp[mf][q] += __builtin_amdgcn_exp2f(accA[mf][q]);
      }
      // MFMAs for group g -> accA
#pragma unroll
      for (int mf = 0; mf < 4; ++mf) {
        f32x4 t = __builtin_amdgcn_mfma_scale_f32_16x16x128_f8f6f4(
            a8[mf][0], b0[g % 3], zero4, 0, 0, 0, 127, 0, 127);
        accA[mf] = __builtin_amdgcn_mfma_scale_f32_16x16x128_f8f6f4(
            a8[mf][1], b1[g % 3], t, 0, 0, 0, 127, 0, 127);
      }
    } else {
      if (g >= 2) {
#pragma unroll
        for (int mf = 0; mf < 4; ++mf)
#pragma unroll
          for (int q = 0; q < 4; ++q)
            Sp[mf][q] += __builtin_amdgcn_exp2f(accB[mf][q]);
      }
      // MFMAs for group g -> accB
#pragma unroll
      for (int mf = 0; mf < 4; ++mf) {
        f32x4 t = __builtin_amdgcn_mfma_scale_f32_16x16x128_f8f6f4(
            a8[mf][0], b0[g % 3], zero4, 0, 0, 0, 127, 0, 127);
        accB[mf] = __builtin_amdgcn_mfma_scale_f32_16x16x128_f8f6f4(
            a8[mf][1], b1[g % 3], t, 0, 0, 0, 127, 0, 127);
      }
    }
  }
  // epilogue: harvest the last two groups (g=30 -> accA, g=31 -> accB)
#pragma unroll
  for (int mf = 0; mf < 4; ++mf)
#pragma unroll
    for (int q = 0; q < 4; ++q)
      Sp[mf][q] += __builtin_amdgcn_exp2f(accA[mf][q])
                 + __builtin_amdgcn_exp2f(accB[mf][q]);

  // reduce across the 16 key-columns (lanes sharing l4)
#pragma unroll
  for (int mf = 0; mf < 4; ++mf)
#pragma unroll
    for (int q = 0; q < 4; ++q) {
      float v = Sp[mf][q];
      v += __shfl_xor(v, 1); v += __shfl_xor(v, 2);
      v += __shfl_xor(v, 4); v += __shfl_xor(v, 8);
      Sp[mf][q] = v;
    }

  // block-level reduce in LDS (8 waves share the same 64 rows), then
  // one global atomic per row (4 slices -> 4 atomics/row total).
  __syncthreads();                         // sred init visible
  if (l15 == 0) {
#pragma unroll
    for (int mf = 0; mf < 4; ++mf)
#pragma unroll
      for (int q = 0; q < 4; ++q)
        atomicAdd(&sred[mf * 16 + l4 * 4 + q], Sp[mf][q]);
  }
  __syncthreads();
  if (tid < 64) atomicAdd(&S[m0 + tid], sred[tid]);
}

// ---------------------------------------------------------------------------
// Kernel 3: loss partials -> atomicAdd(out). 32 blocks x 256 thr = 1 row/thr.
// ---------------------------------------------------------------------------
__global__ __launch_bounds__(256) void finalize_kernel(
    const float* __restrict__ S, const float* __restrict__ Pterm,
    const float* __restrict__ diagsub, float* __restrict__ out)
{
  const int i = blockIdx.x * 256 + threadIdx.x;
  float v = S[i] - diagsub[i];
  float acc = logf(fmaxf(v, 1e-20f)) - Pterm[i];
#pragma unroll
  for (int m = 1; m < 64; m <<= 1) acc += __shfl_xor(acc, m);
  __shared__ float w[4];
  if ((threadIdx.x & 63) == 0) w[threadIdx.x >> 6] = acc;
  __syncthreads();
  if (threadIdx.x == 0)
    atomicAdd(out, (w[0] + w[1] + w[2] + w[3]) * (1.0f / (float)NROWS));
}

// ---------------------------------------------------------------------------
extern "C" void kernel_launch(void* const* d_in, const int* in_sizes, int n_in,
                              void* d_out, int out_size, void* d_ws, size_t ws_size,
                              hipStream_t stream) {
  const float* h  = (const float*)d_in[0];
  const float* hg = (const float*)d_in[1];

  char* ws = (char*)d_ws;
  const size_t OFF_QS   = 0;                      // 2 MB (8192*256 fp8)
  const size_t OFF_KEYS = (size_t)2 << 20;        // 4 MB (16384*256 fp8)
  const size_t OFF_P    = (size_t)6 << 20;        // 32 KB
  const size_t OFF_DIAG = OFF_P + 32 * 1024;      // 32 KB
  const size_t OFF_S    = OFF_DIAG + 32 * 1024;   // 32 KB
  const size_t NEED     = OFF_S + 32 * 1024;
  if (ws_size < NEED) return;

  unsigned int* qs8   = (unsigned int*)(ws + OFF_QS);
  unsigned int* keys8 = (unsigned int*)(ws + OFF_KEYS);
  float* Pterm   = (float*)(ws + OFF_P);
  float* diagsub = (float*)(ws + OFF_DIAG);
  float* S       = (float*)(ws + OFF_S);

  prep_kernel<<<2048, 256, 0, stream>>>(h, hg, qs8, keys8, Pterm, diagsub, S,
                                        (float*)d_out);
  nce_gemm<<<512, 512, 0, stream>>>(qs8, keys8, S);
  finalize_kernel<<<32, 256, 0, stream>>>(S, Pterm, diagsub, (float*)d_out);
}

// Round 24
// 55.471 us; speedup vs baseline: 1.1634x; 1.0071x over previous
//
#include <hip/hip_runtime.h>

// ---------- types ----------
typedef __attribute__((ext_vector_type(4))) float float4_;
typedef __attribute__((ext_vector_type(4))) float f32x4;
typedef __attribute__((ext_vector_type(8))) int   i32x8;
typedef __attribute__((ext_vector_type(2))) unsigned int uint2_;

#define NROWS 8192
#define NKEYS 16384
#define DDIM  256

// exp(x/T) == exp2(x * C_SC)
static constexpr float T_INV = (float)(1.0 / 0.07);
static constexpr float C_SC  = (float)(1.0 / (0.07 * 0.6931471805599453));

// ---------------------------------------------------------------------------
// Fragment-linear key layout (verified r8-r23): key-group G = 16 keys.
// Byte addr of (key k, dim d):
//   (k>>4)*4096 + (d>>7)*2048 + ((d>>5)&3)*512 + (k&15)*32 + (d&31)
// Gemm read: lane l = l4*16+l15 reads 32B at G*4096 + kk*2048 + l*32 =
// key G*16+l15, dims [kk*128 + l4*32, +32) — same formula. Rule #21: one
// convention, both sides (algebra re-verified for the 8B-store writer).
// ---------------------------------------------------------------------------

// ---------------------------------------------------------------------------
// Kernel 1 (RESTRUCTURED r24): 32 lanes per row, 2 rows/wave, 8 dims/lane.
//   - key stores widen 4B->8B contiguous (was the half-line scatter)
//   - shuffle reduce 6->5 rounds (xor 1,2,4,8,16 within 32-lane halves)
//   - grid 1024 x 256 (8 rows/block)
// Emits: qs8 [8192][256] fp8 (scaled C_SC, natural); keys8 fragment-linear
// (q keys 0..8191, g keys 8192..16383); Pterm = dot_f32(q,g)/T;
// diagsub = exp2 of fp8-level qq diagonal. Zeroes S and out[0].
// ---------------------------------------------------------------------------
__global__ __launch_bounds__(256) void prep_kernel(
    const float* __restrict__ h, const float* __restrict__ g,
    unsigned int* __restrict__ qs8, unsigned int* __restrict__ keys8,
    float* __restrict__ Pterm, float* __restrict__ diagsub,
    float* __restrict__ S, float* __restrict__ out)
{
  const int row    = blockIdx.x * 8 + (threadIdx.x >> 5);
  const int lane32 = threadIdx.x & 31;     // 8 dims each

  const float4_* hp = (const float4_*)h + (size_t)row * 64 + lane32 * 2;
  const float4_* gp = (const float4_*)g + (size_t)row * 64 + lane32 * 2;
  float4_ hv0 = hp[0], hv1 = hp[1];
  float4_ gv0 = gp[0], gv1 = gp[1];

  float ssh = hv0.x*hv0.x + hv0.y*hv0.y + hv0.z*hv0.z + hv0.w*hv0.w
            + hv1.x*hv1.x + hv1.y*hv1.y + hv1.z*hv1.z + hv1.w*hv1.w;
  float ssg = gv0.x*gv0.x + gv0.y*gv0.y + gv0.z*gv0.z + gv0.w*gv0.w
            + gv1.x*gv1.x + gv1.y*gv1.y + gv1.z*gv1.z + gv1.w*gv1.w;
#pragma unroll
  for (int m = 1; m < 32; m <<= 1) {       // 32-lane reduce (xor<32 stays
    ssh += __shfl_xor(ssh, m);             //  within each half-wave)
    ssg += __shfl_xor(ssg, m);
  }
  const float sh = 1.0f / fmaxf(sqrtf(ssh), 1e-8f);
  const float sg = 1.0f / fmaxf(sqrtf(ssg), 1e-8f);

  float qn[8] = { hv0.x*sh, hv0.y*sh, hv0.z*sh, hv0.w*sh,
                  hv1.x*sh, hv1.y*sh, hv1.z*sh, hv1.w*sh };
  float gn[8] = { gv0.x*sg, gv0.y*sg, gv0.z*sg, gv0.w*sg,
                  gv1.x*sg, gv1.y*sg, gv1.z*sg, gv1.w*sg };

  float pd = 0.0f;
#pragma unroll
  for (int j = 0; j < 8; ++j) pd += qn[j] * gn[j];

  // fp8 packs (RNE, saturating). word_sel / byte_sel must be literals.
  int ps0 = __builtin_amdgcn_cvt_pk_fp8_f32(qn[0]*C_SC, qn[1]*C_SC, 0, 0);
  ps0     = __builtin_amdgcn_cvt_pk_fp8_f32(qn[2]*C_SC, qn[3]*C_SC, ps0, 1);
  int ps1 = __builtin_amdgcn_cvt_pk_fp8_f32(qn[4]*C_SC, qn[5]*C_SC, 0, 0);
  ps1     = __builtin_amdgcn_cvt_pk_fp8_f32(qn[6]*C_SC, qn[7]*C_SC, ps1, 1);
  int pq0 = __builtin_amdgcn_cvt_pk_fp8_f32(qn[0], qn[1], 0, 0);
  pq0     = __builtin_amdgcn_cvt_pk_fp8_f32(qn[2], qn[3], pq0, 1);
  int pq1 = __builtin_amdgcn_cvt_pk_fp8_f32(qn[4], qn[5], 0, 0);
  pq1     = __builtin_amdgcn_cvt_pk_fp8_f32(qn[6], qn[7], pq1, 1);
  int pg0 = __builtin_amdgcn_cvt_pk_fp8_f32(gn[0], gn[1], 0, 0);
  pg0     = __builtin_amdgcn_cvt_pk_fp8_f32(gn[2], gn[3], pg0, 1);
  int pg1 = __builtin_amdgcn_cvt_pk_fp8_f32(gn[4], gn[5], 0, 0);
  pg1     = __builtin_amdgcn_cvt_pk_fp8_f32(gn[6], gn[7], pg1, 1);

  float dd =
      __builtin_amdgcn_cvt_f32_fp8(ps0,0) * __builtin_amdgcn_cvt_f32_fp8(pq0,0)
    + __builtin_amdgcn_cvt_f32_fp8(ps0,1) * __builtin_amdgcn_cvt_f32_fp8(pq0,1)
    + __builtin_amdgcn_cvt_f32_fp8(ps0,2) * __builtin_amdgcn_cvt_f32_fp8(pq0,2)
    + __builtin_amdgcn_cvt_f32_fp8(ps0,3) * __builtin_amdgcn_cvt_f32_fp8(pq0,3)
    + __builtin_amdgcn_cvt_f32_fp8(ps1,0) * __builtin_amdgcn_cvt_f32_fp8(pq1,0)
    + __builtin_amdgcn_cvt_f32_fp8(ps1,1) * __builtin_amdgcn_cvt_f32_fp8(pq1,1)
    + __builtin_amdgcn_cvt_f32_fp8(ps1,2) * __builtin_amdgcn_cvt_f32_fp8(pq1,2)
    + __builtin_amdgcn_cvt_f32_fp8(ps1,3) * __builtin_amdgcn_cvt_f32_fp8(pq1,3);

#pragma unroll
  for (int m = 1; m < 32; m <<= 1) {
    pd += __shfl_xor(pd, m);
    dd += __shfl_xor(dd, m);
  }

  // qs8: natural layout, 8B/lane contiguous
  uint2_ vs = { (unsigned int)ps0, (unsigned int)ps1 };
  *((uint2_*)(qs8 + (size_t)row * 64 + lane32 * 2)) = vs;

  // fragment-linear key writes, 8B contiguous per lane:
  // d0 = lane32*8; addr = (k>>4)*4096 + (d0>>7)*2048 + ((d0>>5)&3)*512
  //                      + (k&15)*32 + (d0&31)
  char* kb = (char*)keys8;
  const int foff = ((lane32 >> 4) << 11) + (((lane32 >> 2) & 3) << 9)
                 + ((lane32 & 3) << 3);
  {
    const int k = row;                     // q keys (global key idx == row)
    uint2_ v = { (unsigned int)pq0, (unsigned int)pq1 };
    *(uint2_*)(kb + (((size_t)(k >> 4)) << 12) + foff + ((k & 15) << 5)) = v;
  }
  {
    const int k = NROWS + row;             // g keys
    uint2_ v = { (unsigned int)pg0, (unsigned int)pg1 };
    *(uint2_*)(kb + (((size_t)(k >> 4)) << 12) + foff + ((k & 15) << 5)) = v;
  }

  if (lane32 == 0) {
    Pterm[row]   = pd * T_INV;
    diagsub[row] = __builtin_amdgcn_exp2f(dd);
    S[row]       = 0.0f;
    if (row == 0) out[0] = 0.0f;           // finalize accumulates atomically
  }
}

// ---------------------------------------------------------------------------
// Kernel 2: fused MX-fp8 GEMM (16x16x128) + exp2 + row-sum — byte-identical
// to verified r23 (parity-split accs, depth-2 B-prefetch, no LDS staging,
// no main-loop barriers, BM=64, grid 512). Structurally converged at
// ~43 us = 1.62 PF, matching the guide's m148 simple-structure MX-fp8
// plateau (1628 TF); 7 independent levers all null (r13-r23 ledger).
// ---------------------------------------------------------------------------
__global__ __launch_bounds__(512, 1) void nce_gemm(
    const unsigned int* __restrict__ qs8,
    const unsigned int* __restrict__ keys8,
    float* __restrict__ S)
{
  __shared__ float sred[64];               // end-of-kernel reduce only

  const int tid  = threadIdx.x;
  const int wid  = tid >> 6;
  const int lane = tid & 63;
  const int l15  = lane & 15, l4 = lane >> 4;

  const int bid   = blockIdx.x;
  const int slice = bid & 3;               // constant per XCD
  const int mtile = bid >> 2;              // 0..127
  const int m0    = mtile * 64;            // all 8 waves share these 64 rows

  if (tid < 64) sred[tid] = 0.0f;

  // ---- A fragments: 4 mf x 2 kk x 32B ; K elem = kk*128 + l4*32 + j ----
  const char* qb = (const char*)qs8;
  i32x8 a8[4][2];
#pragma unroll
  for (int mf = 0; mf < 4; ++mf) {
    const char* rp = qb + (size_t)(m0 + mf * 16 + l15) * 256 + l4 * 32;
#pragma unroll
    for (int kk = 0; kk < 2; ++kk)
      a8[mf][kk] = *(const i32x8*)(rp + kk * 128);
  }

  const f32x4 zero4 = { 0.f, 0.f, 0.f, 0.f };
  f32x4 accA[4], accB[4];                  // parity-split accumulator sets
  float Sp[4][4] = {};                     // [mf][q] row-sums

  // wave's private key range: 512 keys = 32 groups of 16
  const char* kp = (const char*)keys8
      + (((size_t)(slice * 256 + wid * 32)) << 12) + (size_t)lane * 32;

  // ---- depth-2 B-prefetch: 3-slot rotating buffer (verified r19) ----
  i32x8 b0[3], b1[3];
  b0[0] = *(const i32x8*)(kp);
  b1[0] = *(const i32x8*)(kp + 2048);
  b0[1] = *(const i32x8*)(kp + 4096);
  b1[1] = *(const i32x8*)(kp + 4096 + 2048);

#pragma unroll
  for (int g = 0; g < 32; ++g) {
    if (g + 2 < 32) {                      // prefetch g+2 (compile-time slot)
      b0[(g + 2) % 3] = *(const i32x8*)(kp + ((size_t)(g + 2) << 12));
      b1[(g + 2) % 3] = *(const i32x8*)(kp + ((size_t)(g + 2) << 12) + 2048);
    }

    // harvest the SAME-PARITY acc produced at iteration g-2 (~480cy old),
    // BEFORE this iteration's MFMAs overwrite it (WAR -> renaming-safe).
    if ((g & 1) == 0) {
      if (g >= 2) {
#pragma unroll
        for (int mf = 0; mf < 4; ++mf)
#pragma unroll
          for (int q = 0; q < 4; ++q)
            Sp[mf][q] += __builtin_amdgcn_exp2f(accA[mf][q]);
      }
#pragma unroll
      for (int mf = 0; mf < 4; ++mf) {
        f32x4 t = __builtin_amdgcn_mfma_scale_f32_16x16x128_f8f6f4(
            a8[mf][0], b0[g % 3], zero4, 0, 0, 0, 127, 0, 127);
        accA[mf] = __builtin_amdgcn_mfma_scale_f32_16x16x128_f8f6f4(
            a8[mf][1], b1[g % 3], t, 0, 0, 0, 127, 0, 127);
      }
    } else {
      if (g >= 2) {
#pragma unroll
        for (int mf = 0; mf < 4; ++mf)
#pragma unroll
          for (int q = 0; q < 4; ++q)
            Sp[mf][q] += __builtin_amdgcn_exp2f(accB[mf][q]);
      }
#pragma unroll
      for (int mf = 0; mf < 4; ++mf) {
        f32x4 t = __builtin_amdgcn_mfma_scale_f32_16x16x128_f8f6f4(
            a8[mf][0], b0[g % 3], zero4, 0, 0, 0, 127, 0, 127);
        accB[mf] = __builtin_amdgcn_mfma_scale_f32_16x16x128_f8f6f4(
            a8[mf][1], b1[g % 3], t, 0, 0, 0, 127, 0, 127);
      }
    }
  }
  // epilogue: harvest the last two groups (g=30 -> accA, g=31 -> accB)
#pragma unroll
  for (int mf = 0; mf < 4; ++mf)
#pragma unroll
    for (int q = 0; q < 4; ++q)
      Sp[mf][q] += __builtin_amdgcn_exp2f(accA[mf][q])
                 + __builtin_amdgcn_exp2f(accB[mf][q]);

  // reduce across the 16 key-columns (lanes sharing l4)
#pragma unroll
  for (int mf = 0; mf < 4; ++mf)
#pragma unroll
    for (int q = 0; q < 4; ++q) {
      float v = Sp[mf][q];
      v += __shfl_xor(v, 1); v += __shfl_xor(v, 2);
      v += __shfl_xor(v, 4); v += __shfl_xor(v, 8);
      Sp[mf][q] = v;
    }

  // block-level reduce in LDS (8 waves share the same 64 rows), then
  // one global atomic per row (4 slices -> 4 atomics/row total).
  __syncthreads();                         // sred init visible
  if (l15 == 0) {
#pragma unroll
    for (int mf = 0; mf < 4; ++mf)
#pragma unroll
      for (int q = 0; q < 4; ++q)
        atomicAdd(&sred[mf * 16 + l4 * 4 + q], Sp[mf][q]);
  }
  __syncthreads();
  if (tid < 64) atomicAdd(&S[m0 + tid], sred[tid]);
}

// ---------------------------------------------------------------------------
// Kernel 3: loss partials -> atomicAdd(out). 32 blocks x 256 thr = 1 row/thr.
// ---------------------------------------------------------------------------
__global__ __launch_bounds__(256) void finalize_kernel(
    const float* __restrict__ S, const float* __restrict__ Pterm,
    const float* __restrict__ diagsub, float* __restrict__ out)
{
  const int i = blockIdx.x * 256 + threadIdx.x;
  float v = S[i] - diagsub[i];
  float acc = logf(fmaxf(v, 1e-20f)) - Pterm[i];
#pragma unroll
  for (int m = 1; m < 64; m <<= 1) acc += __shfl_xor(acc, m);
  __shared__ float w[4];
  if ((threadIdx.x & 63) == 0) w[threadIdx.x >> 6] = acc;
  __syncthreads();
  if (threadIdx.x == 0)
    atomicAdd(out, (w[0] + w[1] + w[2] + w[3]) * (1.0f / (float)NROWS));
}

// ---------------------------------------------------------------------------
extern "C" void kernel_launch(void* const* d_in, const int* in_sizes, int n_in,
                              void* d_out, int out_size, void* d_ws, size_t ws_size,
                              hipStream_t stream) {
  const float* h  = (const float*)d_in[0];
  const float* hg = (const float*)d_in[1];

  char* ws = (char*)d_ws;
  const size_t OFF_QS   = 0;                      // 2 MB (8192*256 fp8)
  const size_t OFF_KEYS = (size_t)2 << 20;        // 4 MB (16384*256 fp8)
  const size_t OFF_P    = (size_t)6 << 20;        // 32 KB
  const size_t OFF_DIAG = OFF_P + 32 * 1024;      // 32 KB
  const size_t OFF_S    = OFF_DIAG + 32 * 1024;   // 32 KB
  const size_t NEED     = OFF_S + 32 * 1024;
  if (ws_size < NEED) return;

  unsigned int* qs8   = (unsigned int*)(ws + OFF_QS);
  unsigned int* keys8 = (unsigned int*)(ws + OFF_KEYS);
  float* Pterm   = (float*)(ws + OFF_P);
  float* diagsub = (float*)(ws + OFF_DIAG);
  float* S       = (float*)(ws + OFF_S);

  prep_kernel<<<1024, 256, 0, stream>>>(h, hg, qs8, keys8, Pterm, diagsub, S,
                                        (float*)d_out);
  nce_gemm<<<512, 512, 0, stream>>>(qs8, keys8, S);
  finalize_kernel<<<32, 256, 0, stream>>>(S, Pterm, diagsub, (float*)d_out);
}

// Round 25
// 51.049 us; speedup vs baseline: 1.2642x; 1.0866x over previous
//
#include <hip/hip_runtime.h>

// ---------- types ----------
typedef __attribute__((ext_vector_type(4))) float float4_;
typedef __attribute__((ext_vector_type(4))) float f32x4;
typedef __attribute__((ext_vector_type(8))) int   i32x8;
typedef __attribute__((ext_vector_type(2))) unsigned int uint2_;

#define NROWS 8192
#define NKEYS 16384
#define DDIM  256

// exp(x/T) == exp2(x * C_SC)
static constexpr float T_INV = (float)(1.0 / 0.07);
static constexpr float C_SC  = (float)(1.0 / (0.07 * 0.6931471805599453));

// ---------------------------------------------------------------------------
// Fragment-linear key layout (verified r8-r24): key-group G = 16 keys.
// Byte addr of (key k, dim d):
//   (k>>4)*4096 + (d>>7)*2048 + ((d>>5)&3)*512 + (k&15)*32 + (d&31)
// Gemm read: lane l = l4*16+l15 reads 32B at G*4096 + kk*2048 + l*32 =
// key G*16+l15, dims [kk*128 + l4*32, +32). Rule #21: one convention.
// ---------------------------------------------------------------------------

// ---------------------------------------------------------------------------
// Kernel 1 (r24, verified): 32 lanes/row, 2 rows/wave, 8 dims/lane; 8B
// contiguous key stores; 5-round shuffle reduce. Emits qs8 (natural,
// C_SC-scaled), keys8 (fragment-linear), Pterm, diagsub (fp8-level qq
// diagonal). Zeroes S and out[0].
// ---------------------------------------------------------------------------
__global__ __launch_bounds__(256) void prep_kernel(
    const float* __restrict__ h, const float* __restrict__ g,
    unsigned int* __restrict__ qs8, unsigned int* __restrict__ keys8,
    float* __restrict__ Pterm, float* __restrict__ diagsub,
    float* __restrict__ S, float* __restrict__ out)
{
  const int row    = blockIdx.x * 8 + (threadIdx.x >> 5);
  const int lane32 = threadIdx.x & 31;     // 8 dims each

  const float4_* hp = (const float4_*)h + (size_t)row * 64 + lane32 * 2;
  const float4_* gp = (const float4_*)g + (size_t)row * 64 + lane32 * 2;
  float4_ hv0 = hp[0], hv1 = hp[1];
  float4_ gv0 = gp[0], gv1 = gp[1];

  float ssh = hv0.x*hv0.x + hv0.y*hv0.y + hv0.z*hv0.z + hv0.w*hv0.w
            + hv1.x*hv1.x + hv1.y*hv1.y + hv1.z*hv1.z + hv1.w*hv1.w;
  float ssg = gv0.x*gv0.x + gv0.y*gv0.y + gv0.z*gv0.z + gv0.w*gv0.w
            + gv1.x*gv1.x + gv1.y*gv1.y + gv1.z*gv1.z + gv1.w*gv1.w;
#pragma unroll
  for (int m = 1; m < 32; m <<= 1) {
    ssh += __shfl_xor(ssh, m);
    ssg += __shfl_xor(ssg, m);
  }
  const float sh = 1.0f / fmaxf(sqrtf(ssh), 1e-8f);
  const float sg = 1.0f / fmaxf(sqrtf(ssg), 1e-8f);

  float qn[8] = { hv0.x*sh, hv0.y*sh, hv0.z*sh, hv0.w*sh,
                  hv1.x*sh, hv1.y*sh, hv1.z*sh, hv1.w*sh };
  float gn[8] = { gv0.x*sg, gv0.y*sg, gv0.z*sg, gv0.w*sg,
                  gv1.x*sg, gv1.y*sg, gv1.z*sg, gv1.w*sg };

  float pd = 0.0f;
#pragma unroll
  for (int j = 0; j < 8; ++j) pd += qn[j] * gn[j];

  // fp8 packs (RNE, saturating). word_sel / byte_sel must be literals.
  int ps0 = __builtin_amdgcn_cvt_pk_fp8_f32(qn[0]*C_SC, qn[1]*C_SC, 0, 0);
  ps0     = __builtin_amdgcn_cvt_pk_fp8_f32(qn[2]*C_SC, qn[3]*C_SC, ps0, 1);
  int ps1 = __builtin_amdgcn_cvt_pk_fp8_f32(qn[4]*C_SC, qn[5]*C_SC, 0, 0);
  ps1     = __builtin_amdgcn_cvt_pk_fp8_f32(qn[6]*C_SC, qn[7]*C_SC, ps1, 1);
  int pq0 = __builtin_amdgcn_cvt_pk_fp8_f32(qn[0], qn[1], 0, 0);
  pq0     = __builtin_amdgcn_cvt_pk_fp8_f32(qn[2], qn[3], pq0, 1);
  int pq1 = __builtin_amdgcn_cvt_pk_fp8_f32(qn[4], qn[5], 0, 0);
  pq1     = __builtin_amdgcn_cvt_pk_fp8_f32(qn[6], qn[7], pq1, 1);
  int pg0 = __builtin_amdgcn_cvt_pk_fp8_f32(gn[0], gn[1], 0, 0);
  pg0     = __builtin_amdgcn_cvt_pk_fp8_f32(gn[2], gn[3], pg0, 1);
  int pg1 = __builtin_amdgcn_cvt_pk_fp8_f32(gn[4], gn[5], 0, 0);
  pg1     = __builtin_amdgcn_cvt_pk_fp8_f32(gn[6], gn[7], pg1, 1);

  float dd =
      __builtin_amdgcn_cvt_f32_fp8(ps0,0) * __builtin_amdgcn_cvt_f32_fp8(pq0,0)
    + __builtin_amdgcn_cvt_f32_fp8(ps0,1) * __builtin_amdgcn_cvt_f32_fp8(pq0,1)
    + __builtin_amdgcn_cvt_f32_fp8(ps0,2) * __builtin_amdgcn_cvt_f32_fp8(pq0,2)
    + __builtin_amdgcn_cvt_f32_fp8(ps0,3) * __builtin_amdgcn_cvt_f32_fp8(pq0,3)
    + __builtin_amdgcn_cvt_f32_fp8(ps1,0) * __builtin_amdgcn_cvt_f32_fp8(pq1,0)
    + __builtin_amdgcn_cvt_f32_fp8(ps1,1) * __builtin_amdgcn_cvt_f32_fp8(pq1,1)
    + __builtin_amdgcn_cvt_f32_fp8(ps1,2) * __builtin_amdgcn_cvt_f32_fp8(pq1,2)
    + __builtin_amdgcn_cvt_f32_fp8(ps1,3) * __builtin_amdgcn_cvt_f32_fp8(pq1,3);

#pragma unroll
  for (int m = 1; m < 32; m <<= 1) {
    pd += __shfl_xor(pd, m);
    dd += __shfl_xor(dd, m);
  }

  // qs8: natural layout, 8B/lane contiguous
  uint2_ vs = { (unsigned int)ps0, (unsigned int)ps1 };
  *((uint2_*)(qs8 + (size_t)row * 64 + lane32 * 2)) = vs;

  // fragment-linear key writes, 8B contiguous per lane
  char* kb = (char*)keys8;
  const int foff = ((lane32 >> 4) << 11) + (((lane32 >> 2) & 3) << 9)
                 + ((lane32 & 3) << 3);
  {
    const int k = row;                     // q keys
    uint2_ v = { (unsigned int)pq0, (unsigned int)pq1 };
    *(uint2_*)(kb + (((size_t)(k >> 4)) << 12) + foff + ((k & 15) << 5)) = v;
  }
  {
    const int k = NROWS + row;             // g keys
    uint2_ v = { (unsigned int)pg0, (unsigned int)pg1 };
    *(uint2_*)(kb + (((size_t)(k >> 4)) << 12) + foff + ((k & 15) << 5)) = v;
  }

  if (lane32 == 0) {
    Pterm[row]   = pd * T_INV;
    diagsub[row] = __builtin_amdgcn_exp2f(dd);
    S[row]       = 0.0f;
    if (row == 0) out[0] = 0.0f;           // finalize accumulates atomically
  }
}

// ---------------------------------------------------------------------------
// Kernel 2: fused MX-fp8 GEMM (16x16x128) + exp2 + row-sum — the r15
// configuration verbatim (session-best measured gemm, 42.4us): no LDS
// staging, no main-loop barriers, BM=64, grid 512, direct B loads,
// launch_bounds(512,4) -> VGPR 60, occupancy ~31%.
// Structurally converged at ~43us = 1.62 PF (guide m148 plateau: 1628 TF);
// eight single-variable levers null (r13-r24 ledger), two co-designed
// schedules toolchain-failed (r20/r21). Issue-port model floor ~25us is
// unreachable without the 8-phase wave-specialized schedule.
// ---------------------------------------------------------------------------
__global__ __launch_bounds__(512, 4) void nce_gemm(
    const unsigned int* __restrict__ qs8,
    const unsigned int* __restrict__ keys8,
    float* __restrict__ S)
{
  __shared__ float sred[64];               // end-of-kernel reduce only

  const int tid  = threadIdx.x;
  const int wid  = tid >> 6;
  const int lane = tid & 63;
  const int l15  = lane & 15, l4 = lane >> 4;

  const int bid   = blockIdx.x;
  const int slice = bid & 3;               // constant per XCD
  const int mtile = bid >> 2;              // 0..127
  const int m0    = mtile * 64;            // all 8 waves share these 64 rows

  if (tid < 64) sred[tid] = 0.0f;

  // ---- A fragments: 4 mf x 2 kk x 32B ; K elem = kk*128 + l4*32 + j ----
  const char* qb = (const char*)qs8;
  i32x8 a8[4][2];
#pragma unroll
  for (int mf = 0; mf < 4; ++mf) {
    const char* rp = qb + (size_t)(m0 + mf * 16 + l15) * 256 + l4 * 32;
#pragma unroll
    for (int kk = 0; kk < 2; ++kk)
      a8[mf][kk] = *(const i32x8*)(rp + kk * 128);
  }

  const f32x4 zero4 = { 0.f, 0.f, 0.f, 0.f };
  f32x4 acc[4];
  float Sp[4][4] = {};                     // [mf][q] row-sums

  // wave's private key range: 512 keys = 32 groups of 16
  const char* kp = (const char*)keys8
      + (((size_t)(slice * 256 + wid * 32)) << 12) + (size_t)lane * 32;

#pragma unroll 2
  for (int g = 0; g < 32; ++g) {
    i32x8 b0 = *(const i32x8*)(kp + ((size_t)g << 12));
    i32x8 b1 = *(const i32x8*)(kp + ((size_t)g << 12) + 2048);

    if (g > 0) {                           // harvest prev group (old acc)
#pragma unroll
      for (int mf = 0; mf < 4; ++mf)
#pragma unroll
        for (int q = 0; q < 4; ++q)
          Sp[mf][q] += __builtin_amdgcn_exp2f(acc[mf][q]);
    }

    // cbsz=0 (A fmt fp8 e4m3), blgp=0 (B fmt fp8), scales 127 = x1.0
#pragma unroll
    for (int mf = 0; mf < 4; ++mf) {
      f32x4 t = __builtin_amdgcn_mfma_scale_f32_16x16x128_f8f6f4(
          a8[mf][0], b0, zero4, 0, 0, 0, 127, 0, 127);
      acc[mf] = __builtin_amdgcn_mfma_scale_f32_16x16x128_f8f6f4(
          a8[mf][1], b1, t, 0, 0, 0, 127, 0, 127);
    }
  }
#pragma unroll
  for (int mf = 0; mf < 4; ++mf)           // last group's harvest
#pragma unroll
    for (int q = 0; q < 4; ++q)
      Sp[mf][q] += __builtin_amdgcn_exp2f(acc[mf][q]);

  // reduce across the 16 key-columns (lanes sharing l4)
#pragma unroll
  for (int mf = 0; mf < 4; ++mf)
#pragma unroll
    for (int q = 0; q < 4; ++q) {
      float v = Sp[mf][q];
      v += __shfl_xor(v, 1); v += __shfl_xor(v, 2);
      v += __shfl_xor(v, 4); v += __shfl_xor(v, 8);
      Sp[mf][q] = v;
    }

  // block-level reduce in LDS (8 waves share the same 64 rows), then
  // one global atomic per row (4 slices -> 4 atomics/row total).
  __syncthreads();                         // sred init visible
  if (l15 == 0) {
#pragma unroll
    for (int mf = 0; mf < 4; ++mf)
#pragma unroll
      for (int q = 0; q < 4; ++q)
        atomicAdd(&sred[mf * 16 + l4 * 4 + q], Sp[mf][q]);
  }
  __syncthreads();
  if (tid < 64) atomicAdd(&S[m0 + tid], sred[tid]);
}

// ---------------------------------------------------------------------------
// Kernel 3: loss partials -> atomicAdd(out). 32 blocks x 256 thr = 1 row/thr.
// ---------------------------------------------------------------------------
__global__ __launch_bounds__(256) void finalize_kernel(
    const float* __restrict__ S, const float* __restrict__ Pterm,
    const float* __restrict__ diagsub, float* __restrict__ out)
{
  const int i = blockIdx.x * 256 + threadIdx.x;
  float v = S[i] - diagsub[i];
  float acc = logf(fmaxf(v, 1e-20f)) - Pterm[i];
#pragma unroll
  for (int m = 1; m < 64; m <<= 1) acc += __shfl_xor(acc, m);
  __shared__ float w[4];
  if ((threadIdx.x & 63) == 0) w[threadIdx.x >> 6] = acc;
  __syncthreads();
  if (threadIdx.x == 0)
    atomicAdd(out, (w[0] + w[1] + w[2] + w[3]) * (1.0f / (float)NROWS));
}

// ---------------------------------------------------------------------------
extern "C" void kernel_launch(void* const* d_in, const int* in_sizes, int n_in,
                              void* d_out, int out_size, void* d_ws, size_t ws_size,
                              hipStream_t stream) {
  const float* h  = (const float*)d_in[0];
  const float* hg = (const float*)d_in[1];

  char* ws = (char*)d_ws;
  const size_t OFF_QS   = 0;                      // 2 MB (8192*256 fp8)
  const size_t OFF_KEYS = (size_t)2 << 20;        // 4 MB (16384*256 fp8)
  const size_t OFF_P    = (size_t)6 << 20;        // 32 KB
  const size_t OFF_DIAG = OFF_P + 32 * 1024;      // 32 KB
  const size_t OFF_S    = OFF_DIAG + 32 * 1024;   // 32 KB
  const size_t NEED     = OFF_S + 32 * 1024;
  if (ws_size < NEED) return;

  unsigned int* qs8   = (unsigned int*)(ws + OFF_QS);
  unsigned int* keys8 = (unsigned int*)(ws + OFF_KEYS);
  float* Pterm   = (float*)(ws + OFF_P);
  float* diagsub = (float*)(ws + OFF_DIAG);
  float* S       = (float*)(ws + OFF_S);

  prep_kernel<<<1024, 256, 0, stream>>>(h, hg, qs8, keys8, Pterm, diagsub, S,
                                        (float*)d_out);
  nce_gemm<<<512, 512, 0, stream>>>(qs8, keys8, S);
  finalize_kernel<<<32, 256, 0, stream>>>(S, Pterm, diagsub, (float*)d_out);
}